// Round 3
// baseline (14552.695 us; speedup 1.0000x reference)
//
#include <hip/hip_runtime.h>
#include <hip/hip_bf16.h>
#include <stdint.h>

#define HID     1024
#define NSTEP   4096
#define NBLK    64
#define WAVES   8
#define THREADS (WAVES * 64)
#define UPW     2          // units per wave -> 64*8*2 = 1024 units

typedef unsigned int u32x4 __attribute__((ext_vector_type(4)));

// ---------------- ws layout ----------------
// [0, 16MiB)              W' = W_hh + W_ih @ W_dec   (4096 x 1024 f32)
// [16MiB, +16KiB)         b' = b_ih+b_hh+W_ih@b_dec  (4096 f32)
// [.. +16KiB)             ginit = W_ih@x + b_ih+b_hh (4096 f32)
// [.. +16KiB)             hbuf: 2 slots x 1024 x u64 {tag,val} pairs
// [16MiB+64KiB, +16MiB)   H history: 4096 x 1024 f32

__device__ __forceinline__ float d4(float4 a, float4 b) {
    return fmaf(a.x, b.x, fmaf(a.y, b.y, fmaf(a.z, b.z, a.w * b.w)));
}

// ---- prep: b', ginit, clear hbuf tags ----
__global__ void k_prep(const float* __restrict__ x, const float* __restrict__ Wih,
                       const float* __restrict__ bih, const float* __restrict__ bhh,
                       const float* __restrict__ bdec,
                       float* __restrict__ bp, float* __restrict__ gi,
                       unsigned long long* __restrict__ hbuf) {
    int i = blockIdx.x * 256 + threadIdx.x;
    if (i < 4096) {
        float base = bih[i] + bhh[i];
        float s_b = base, s_g = base;
#pragma unroll
        for (int d = 0; d < 11; ++d) {
            float w = Wih[i * 11 + d];
            s_b = fmaf(w, bdec[d], s_b);
            s_g = fmaf(w, x[d], s_g);
        }
        bp[i] = s_b;
        gi[i] = s_g;
    }
    int j = i - 4096;
    if (j >= 0 && j < 2048) hbuf[j] = 0ULL;   // clear step tags (both parity slots)
}

// ---- fold: W' = W_hh + W_ih @ W_dec ----
__global__ void k_fold(const float* __restrict__ Wih, const float* __restrict__ Whh,
                       const float* __restrict__ Wdec, float* __restrict__ Wp) {
    int idx = blockIdx.x * 256 + threadIdx.x;       // 0 .. 4M-1
    int r = idx >> 10, k = idx & 1023;
    float acc = Whh[idx];
#pragma unroll
    for (int d = 0; d < 11; ++d)
        acc = fmaf(Wih[r * 11 + d], Wdec[d * HID + k], acc);
    Wp[idx] = acc;
}

// ---- the sequential LSTM recurrence ----
__global__ __launch_bounds__(THREADS, 2) void lstm_seq(
    const float* __restrict__ Wp, const float* __restrict__ bp,
    const float* __restrict__ gi, unsigned long long* hbuf,
    float* __restrict__ Hh) {
    const int tid  = threadIdx.x;
    const int wv   = tid >> 6;
    const int lane = tid & 63;
    const int u0   = (blockIdx.x * WAVES + wv) * UPW;   // this wave owns units u0, u0+1

    // Per-lane weights, conflict-free layout: for gate row r, chunk j (j=0..3),
    // lane holds W'[r*HID + 4*(lane + 64*j) .. +3].  h is read as h4[lane + 64*j].
    const float4* W4 = (const float4*)Wp;
    float4 w[UPW][4][4];
#pragma unroll
    for (int uu = 0; uu < UPW; ++uu)
#pragma unroll
        for (int q = 0; q < 4; ++q) {
            const float4* base = W4 + ((size_t)(u0 + uu) + (size_t)q * 1024) * 256;
#pragma unroll
            for (int j = 0; j < 4; ++j) w[uu][q][j] = base[lane + 64 * j];
        }

    float bpv[UPW][4], giv[UPW][4];
#pragma unroll
    for (int uu = 0; uu < UPW; ++uu)
#pragma unroll
        for (int q = 0; q < 4; ++q) {
            bpv[uu][q] = bp[u0 + uu + q * 1024];
            giv[uu][q] = gi[u0 + uu + q * 1024];
        }

    __shared__ float hs[2][HID];

    float c[UPW] = {0.f, 0.f};
    float hh[UPW];

#pragma unroll 1
    for (int t = 1; t <= NSTEP; ++t) {
        float s[UPW][4];
        if (t == 1) {
            // h_0 = 0: gates are exactly ginit, no sync needed
#pragma unroll
            for (int uu = 0; uu < UPW; ++uu)
#pragma unroll
                for (int q = 0; q < 4; ++q) s[uu][q] = giv[uu][q];
        } else {
            const int slot = (t - 1) & 1;
            // poll: each thread owns one 16B slot = pairs {2*tid, 2*tid+1}
            const unsigned long long* src = hbuf + slot * HID + 2 * tid;
            const unsigned want = (unsigned)(t - 1);
            u32x4 v;
            for (;;) {
                asm volatile("global_load_dwordx4 %0, %1, off sc0 sc1\n\t"
                             "s_waitcnt vmcnt(0)"
                             : "=v"(v) : "v"(src) : "memory");
                if (v.y == want && v.w == want) break;
            }
            *(float2*)&hs[slot][2 * tid] =
                make_float2(__uint_as_float(v.x), __uint_as_float(v.z));
            __syncthreads();

            const float4* h4 = (const float4*)hs[slot];
            float4 h0 = h4[lane], h1 = h4[lane + 64], h2 = h4[lane + 128], h3 = h4[lane + 192];
#pragma unroll
            for (int uu = 0; uu < UPW; ++uu) {
#pragma unroll
                for (int q = 0; q < 4; ++q)
                    s[uu][q] = d4(w[uu][q][0], h0) + d4(w[uu][q][1], h1)
                             + d4(w[uu][q][2], h2) + d4(w[uu][q][3], h3);
            }
#pragma unroll
            for (int m = 32; m >= 1; m >>= 1) {
#pragma unroll
                for (int uu = 0; uu < UPW; ++uu)
#pragma unroll
                    for (int q = 0; q < 4; ++q)
                        s[uu][q] += __shfl_xor(s[uu][q], m);
            }
#pragma unroll
            for (int uu = 0; uu < UPW; ++uu)
#pragma unroll
                for (int q = 0; q < 4; ++q) s[uu][q] += bpv[uu][q];
        }

        // pointwise LSTM (replicated on all 64 lanes; c stays register-resident)
#pragma unroll
        for (int uu = 0; uu < UPW; ++uu) {
            float I = 1.f / (1.f + __expf(-s[uu][0]));
            float F = 1.f / (1.f + __expf(-s[uu][1]));
            float G = 1.f - 2.f / (__expf(2.f * s[uu][2]) + 1.f);   // tanh
            float O = 1.f / (1.f + __expf(-s[uu][3]));
            c[uu] = fmaf(F, c[uu], I * G);
            hh[uu] = O * (1.f - 2.f / (__expf(2.f * c[uu]) + 1.f));
        }

        if (lane == 0) {
            *(float2*)&Hh[(size_t)(t - 1) * HID + u0] = make_float2(hh[0], hh[1]);
            u32x4 pr;
            pr.x = __float_as_uint(hh[0]); pr.y = (unsigned)t;
            pr.z = __float_as_uint(hh[1]); pr.w = (unsigned)t;
            unsigned long long* dst = hbuf + (t & 1) * HID + u0;
            asm volatile("global_store_dwordx4 %0, %1, off sc0 sc1"
                         :: "v"(dst), "v"(pr) : "memory");
        }
    }
}

// ---- decoder over the whole history: out[r][d] = W_dec[d] . H[r] + b_dec[d] ----
__global__ void k_dec(const float* __restrict__ Hh, const float* __restrict__ Wdec,
                      const float* __restrict__ bdec, float* __restrict__ out) {
    int idx = blockIdx.x * 256 + threadIdx.x;
    if (idx >= NSTEP * 11) return;
    int r = idx / 11, d = idx - r * 11;
    const float4* h4 = (const float4*)(Hh + (size_t)r * HID);
    const float4* w4 = (const float4*)(Wdec + (size_t)d * HID);
    float acc = 0.f;
#pragma unroll 4
    for (int k = 0; k < HID / 4; ++k) {
        float4 a = h4[k], b = w4[k];
        acc = fmaf(a.x, b.x, fmaf(a.y, b.y, fmaf(a.z, b.z, fmaf(a.w, b.w, acc))));
    }
    out[idx] = acc + bdec[d];
}

extern "C" void kernel_launch(void* const* d_in, const int* in_sizes, int n_in,
                              void* d_out, int out_size, void* d_ws, size_t ws_size,
                              hipStream_t stream) {
    const float* x    = (const float*)d_in[0];
    const float* Wih  = (const float*)d_in[1];
    const float* Whh  = (const float*)d_in[2];
    const float* bih  = (const float*)d_in[3];
    const float* bhh  = (const float*)d_in[4];
    const float* Wdec = (const float*)d_in[5];
    const float* bdec = (const float*)d_in[6];
    float* out = (float*)d_out;

    char* ws = (char*)d_ws;
    float* Wp = (float*)ws;                                      // 16 MiB
    float* bp = (float*)(ws + (16u << 20));                      // 16 KiB
    float* gi = bp + 4096;                                       // 16 KiB
    unsigned long long* hbuf = (unsigned long long*)(gi + 4096); // 16 KiB
    float* Hh = (float*)(ws + (16u << 20) + (64u << 10));        // 16 MiB

    k_prep<<<24, 256, 0, stream>>>(x, Wih, bih, bhh, bdec, bp, gi, hbuf);
    k_fold<<<(4096 * 1024) / 256, 256, 0, stream>>>(Wih, Whh, Wdec, Wp);
    lstm_seq<<<NBLK, THREADS, 0, stream>>>(Wp, bp, gi, hbuf, Hh);
    k_dec<<<(NSTEP * 11 + 255) / 256, 256, 0, stream>>>(Hh, Wdec, bdec, out);
}

// Round 4
// 12859.793 us; speedup vs baseline: 1.1316x; 1.1316x over previous
//
#include <hip/hip_runtime.h>
#include <hip/hip_bf16.h>
#include <stdint.h>

#define HID     1024
#define NSTEP   4096
#define NBLK    128
#define WAVES   8
#define THREADS (WAVES * 64)
#define NREP    4          // hbuf replicas (contention fix)

typedef unsigned int u32x4 __attribute__((ext_vector_type(4)));
typedef unsigned int u32x2 __attribute__((ext_vector_type(2)));

// ---------------- ws layout ----------------
// [0, 16MiB)               W' = W_hh + W_ih @ W_dec   (4096 x 1024 f32)
// [16MiB, +16KiB)          b' = b_ih+b_hh+W_ih@b_dec  (4096 f32)
// [.. +16KiB)              ginit = W_ih@x + b_ih+b_hh (4096 f32)
// [.. +64KiB)              hbuf: 4 replicas x 2 slots x 1024 x u64 {val,tag}
// [16MiB+128KiB, +16MiB)   H history: 4096 x 1024 f32

__device__ __forceinline__ float d4(float4 a, float4 b) {
    return fmaf(a.x, b.x, fmaf(a.y, b.y, fmaf(a.z, b.z, a.w * b.w)));
}

// ---- prep: b', ginit, clear all replica tags ----
__global__ void k_prep(const float* __restrict__ x, const float* __restrict__ Wih,
                       const float* __restrict__ bih, const float* __restrict__ bhh,
                       const float* __restrict__ bdec,
                       float* __restrict__ bp, float* __restrict__ gi,
                       unsigned long long* __restrict__ hbuf) {
    int i = blockIdx.x * 256 + threadIdx.x;   // 0 .. 8191
    if (i < 4096) {
        float base = bih[i] + bhh[i];
        float s_b = base, s_g = base;
#pragma unroll
        for (int d = 0; d < 11; ++d) {
            float w = Wih[i * 11 + d];
            s_b = fmaf(w, bdec[d], s_b);
            s_g = fmaf(w, x[d], s_g);
        }
        bp[i] = s_b;
        gi[i] = s_g;
    }
    if (i < NREP * 2 * 1024) hbuf[i] = 0ULL;  // clear tags in all replicas/slots
}

// ---- fold: W' = W_hh + W_ih @ W_dec ----
__global__ void k_fold(const float* __restrict__ Wih, const float* __restrict__ Whh,
                       const float* __restrict__ Wdec, float* __restrict__ Wp) {
    int idx = blockIdx.x * 256 + threadIdx.x;       // 0 .. 4M-1
    int r = idx >> 10, k = idx & 1023;
    float acc = Whh[idx];
#pragma unroll
    for (int d = 0; d < 11; ++d)
        acc = fmaf(Wih[r * 11 + d], Wdec[d * HID + k], acc);
    Wp[idx] = acc;
}

// ---- the sequential LSTM recurrence ----
__global__ __launch_bounds__(THREADS) void lstm_seq(
    const float* __restrict__ Wp, const float* __restrict__ bp,
    const float* __restrict__ gi, unsigned long long* hbuf,
    float* __restrict__ Hh) {
    const int tid  = threadIdx.x;
    const int wv   = tid >> 6;
    const int lane = tid & 63;
    const int u0   = blockIdx.x * WAVES + wv;       // this wave owns unit u0
    const int rep  = blockIdx.x & (NREP - 1);       // which replica this block polls

    // Per-lane weights, conflict-free layout: gate q, chunk j: lane holds
    // W'[(u0+q*1024)*HID + 4*(lane+64*j) .. +3]; h read as h4[lane+64*j].
    const float4* W4 = (const float4*)Wp;
    float4 w[4][4];
#pragma unroll
    for (int q = 0; q < 4; ++q) {
        const float4* base = W4 + ((size_t)u0 + (size_t)q * 1024) * 256;
#pragma unroll
        for (int j = 0; j < 4; ++j) w[q][j] = base[lane + 64 * j];
    }

    float bpv[4], giv[4];
#pragma unroll
    for (int q = 0; q < 4; ++q) {
        bpv[q] = bp[u0 + q * 1024];
        giv[q] = gi[u0 + q * 1024];
    }

    __shared__ float hs[2][HID];

    float c = 0.f;

#pragma unroll 1
    for (int t = 1; t <= NSTEP; ++t) {
        float s[4];
        if (t == 1) {
            // h_0 = 0: gates are exactly ginit, no sync needed
#pragma unroll
            for (int q = 0; q < 4; ++q) s[q] = giv[q];
        } else {
            const int slot = (t - 1) & 1;
            // poll this block's replica: thread owns 16B = pairs {2tid, 2tid+1}
            const unsigned long long* src =
                hbuf + (size_t)rep * 2048 + slot * HID + 2 * tid;
            const unsigned want = (unsigned)(t - 1);
            u32x4 v;
            do {
                asm volatile("global_load_dwordx4 %0, %1, off sc1\n\t"
                             "s_waitcnt vmcnt(0)"
                             : "=v"(v) : "v"(src) : "memory");
                __builtin_amdgcn_sched_barrier(0);
            } while (v.y != want || v.w != want);
            *(float2*)&hs[slot][2 * tid] =
                make_float2(__uint_as_float(v.x), __uint_as_float(v.z));
            __syncthreads();

            const float4* h4 = (const float4*)hs[slot];
            float4 h0 = h4[lane], h1 = h4[lane + 64], h2 = h4[lane + 128], h3 = h4[lane + 192];
#pragma unroll
            for (int q = 0; q < 4; ++q)
                s[q] = d4(w[q][0], h0) + d4(w[q][1], h1)
                     + d4(w[q][2], h2) + d4(w[q][3], h3);
#pragma unroll
            for (int m = 32; m >= 1; m >>= 1) {
#pragma unroll
                for (int q = 0; q < 4; ++q) s[q] += __shfl_xor(s[q], m);
            }
#pragma unroll
            for (int q = 0; q < 4; ++q) s[q] += bpv[q];
        }

        // pointwise LSTM (replicated on all 64 lanes; c stays register-resident)
        float I = 1.f / (1.f + __expf(-s[0]));
        float F = 1.f / (1.f + __expf(-s[1]));
        float G = 1.f - 2.f / (__expf(2.f * s[2]) + 1.f);   // tanh
        float O = 1.f / (1.f + __expf(-s[3]));
        c = fmaf(F, c, I * G);
        float h = O * (1.f - 2.f / (__expf(2.f * c) + 1.f));

        if (lane == 0) {
            Hh[(size_t)(t - 1) * HID + u0] = h;   // history for decoder (plain store)
            u32x2 pr;
            pr.x = __float_as_uint(h);
            pr.y = (unsigned)t;
            unsigned long long* d0 = hbuf + (t & 1) * HID + u0;
            asm volatile("global_store_dwordx2 %0, %4, off sc1\n\t"
                         "global_store_dwordx2 %1, %4, off sc1\n\t"
                         "global_store_dwordx2 %2, %4, off sc1\n\t"
                         "global_store_dwordx2 %3, %4, off sc1"
                         :: "v"(d0), "v"(d0 + 2048), "v"(d0 + 4096), "v"(d0 + 6144),
                            "v"(pr) : "memory");
        }
    }
}

// ---- decoder over the whole history: out[r][d] = W_dec[d] . H[r] + b_dec[d] ----
__global__ void k_dec(const float* __restrict__ Hh, const float* __restrict__ Wdec,
                      const float* __restrict__ bdec, float* __restrict__ out) {
    int idx = blockIdx.x * 256 + threadIdx.x;
    if (idx >= NSTEP * 11) return;
    int r = idx / 11, d = idx - r * 11;
    const float4* h4 = (const float4*)(Hh + (size_t)r * HID);
    const float4* w4 = (const float4*)(Wdec + (size_t)d * HID);
    float acc = 0.f;
#pragma unroll 4
    for (int k = 0; k < HID / 4; ++k) {
        float4 a = h4[k], b = w4[k];
        acc = fmaf(a.x, b.x, fmaf(a.y, b.y, fmaf(a.z, b.z, fmaf(a.w, b.w, acc))));
    }
    out[idx] = acc + bdec[d];
}

extern "C" void kernel_launch(void* const* d_in, const int* in_sizes, int n_in,
                              void* d_out, int out_size, void* d_ws, size_t ws_size,
                              hipStream_t stream) {
    const float* x    = (const float*)d_in[0];
    const float* Wih  = (const float*)d_in[1];
    const float* Whh  = (const float*)d_in[2];
    const float* bih  = (const float*)d_in[3];
    const float* bhh  = (const float*)d_in[4];
    const float* Wdec = (const float*)d_in[5];
    const float* bdec = (const float*)d_in[6];
    float* out = (float*)d_out;

    char* ws = (char*)d_ws;
    float* Wp = (float*)ws;                                      // 16 MiB
    float* bp = (float*)(ws + (16u << 20));                      // 16 KiB
    float* gi = bp + 4096;                                       // 16 KiB
    unsigned long long* hbuf = (unsigned long long*)(gi + 4096); // 64 KiB (4 replicas)
    float* Hh = (float*)(ws + (16u << 20) + (128u << 10));       // 16 MiB

    k_prep<<<32, 256, 0, stream>>>(x, Wih, bih, bhh, bdec, bp, gi, hbuf);
    k_fold<<<(4096 * 1024) / 256, 256, 0, stream>>>(Wih, Whh, Wdec, Wp);
    lstm_seq<<<NBLK, THREADS, 0, stream>>>(Wp, bp, gi, hbuf, Hh);
    k_dec<<<(NSTEP * 11 + 255) / 256, 256, 0, stream>>>(Hh, Wdec, bdec, out);
}